// Round 5
// baseline (203.668 us; speedup 1.0000x reference)
//
#include <hip/hip_runtime.h>
#include <hip/hip_bf16.h>
#include <cmath>
#include <complex>

// Problem constants
constexpr int TT  = 50;            // time length
constexpr int NB  = 50;            // batch
constexpr int NC  = 4096;          // channels
constexpr int NCH = NB * NC;       // 204800 independent series
constexpr int PAD = 49;
constexpr int EXT = TT + 2 * PAD;  // 148

struct Coefs {
    double b0[2][2], b1[2][2], b2[2][2], a1[2][2], a2[2][2];
    double zi0[2][2], zi1[2][2];
};

// ---------------- Setup kernel: build the 50x50 filtfilt+demean matrix per band ----
// (unchanged from round 4 — sections fused elementwise, fwd writes LDS, bwd reads;
// never appeared in rocprof top-5, so it is small.)
__global__ void __launch_bounds__(64, 1) build_M(float* __restrict__ Mt, Coefs cf) {
    __shared__ float ylds[EXT][TT];
    const int band = blockIdx.x;
    const int j = threadIdx.x;
    if (j >= TT) return;

    const double b00 = cf.b0[band][0], b10 = cf.b1[band][0], b20 = cf.b2[band][0];
    const double a10 = cf.a1[band][0], a20 = cf.a2[band][0];
    const double b01 = cf.b0[band][1], b11 = cf.b1[band][1], b21 = cf.b2[band][1];
    const double a11 = cf.a1[band][1], a21 = cf.a2[band][1];

    const double x0 = 2.0 * (j == 0 ? 1.0 : 0.0) - (j == PAD ? 1.0 : 0.0);

    double s00 = cf.zi0[band][0] * x0, s01 = cf.zi1[band][0] * x0;
    double s10 = cf.zi0[band][1] * x0, s11 = cf.zi1[band][1] * x0;
    double ylast = 0.0;
#pragma unroll
    for (int i = 0; i < EXT; ++i) {
        double xt;
        if (i < PAD)            xt = 2.0 * (j == 0 ? 1.0 : 0.0) - (j == PAD - i ? 1.0 : 0.0);
        else if (i < PAD + TT)  xt = (j == i - PAD) ? 1.0 : 0.0;
        else                    xt = 2.0 * (j == TT - 1 ? 1.0 : 0.0)
                                     - (j == 2 * TT - 2 - (i - PAD) ? 1.0 : 0.0);
        const double y0 = b00 * xt + s00;
        s00 = b10 * xt + s01 - a10 * y0;
        s01 = b20 * xt - a20 * y0;
        const double y1 = b01 * y0 + s10;
        s10 = b11 * y0 + s11 - a11 * y1;
        s11 = b21 * y0 - a21 * y1;
        ylds[i][j] = (float)y1;
        if (i == EXT - 1) ylast = y1;
    }

    s00 = cf.zi0[band][0] * ylast; s01 = cf.zi1[band][0] * ylast;
    s10 = cf.zi0[band][1] * ylast; s11 = cf.zi1[band][1] * ylast;
    float o[TT];
#pragma unroll
    for (int m = 0; m < EXT; ++m) {
        const int i = EXT - 1 - m;
        const double xt = (double)ylds[i][j];
        const double y0 = b00 * xt + s00;
        s00 = b10 * xt + s01 - a10 * y0;
        s01 = b20 * xt - a20 * y0;
        const double y1 = b01 * y0 + s10;
        s10 = b11 * y0 + s11 - a11 * y1;
        s11 = b21 * y0 - a21 * y1;
        if (i >= PAD && i < PAD + TT) o[i - PAD] = (float)y1;
    }

    float mean = 0.f;
#pragma unroll
    for (int t = 0; t < TT; ++t) mean += o[t];
    mean *= (1.0f / TT);
#pragma unroll
    for (int t = 0; t < TT; ++t)
        Mt[(band * TT + j) * TT + t] = o[t] - mean;
}

// ---------------- Kernel S: per-series stats (both bands) ---------------------------
// Block 256 = (64 c) x (4 b): waves are c-pure -> 256-B coalesced x loads; M indices
// are thread-independent -> s_load. 832 blocks, ~7 waves/SIMD (vs round 4's 3.1) for
// real latency hiding. Writes only the 3.3 MB float2 {mu, inv} table, no y traffic.
__global__ void __launch_bounds__(256)
stats_k(const float* __restrict__ x, const float* __restrict__ Mt,
        float2* __restrict__ st) {
    const int c = blockIdx.x * 64 + threadIdx.x;
    const int b = blockIdx.y * 4 + threadIdx.y;
    if (b >= NB) return;
    const int i = b * NC + c;

#pragma unroll 1
    for (int band = 0; band < 2; ++band) {
        const float* __restrict__ Mb = Mt + band * TT * TT;
        float f[TT];
#pragma unroll
        for (int t = 0; t < TT; ++t) f[t] = 0.f;
#pragma unroll
        for (int k = 0; k < TT; ++k) {
            const float xk = x[(size_t)k * NCH + i];
#pragma unroll
            for (int t = 0; t < TT; ++t) f[t] = fmaf(Mb[k * TT + t], xk, f[t]);
        }
        float mu = 0.f;
#pragma unroll
        for (int t = 0; t < TT; ++t) mu += f[t];
        mu *= (1.0f / TT);
        float ss = 0.f;
#pragma unroll
        for (int t = 0; t < TT; ++t) {
            const float h = f[t] - mu;
            ss = fmaf(h, h, ss);
        }
        st[(size_t)(band * NB + b) * NC + c] =
            make_float2(mu, 1.0f / sqrtf(ss * (1.0f / (TT - 1))));
    }
}

// ---------------- Kernel O: recompute y, apply quirk normalization ------------------
// Same clean inner loop (compute is ~13 us chip-wide, recomputing beats an 80 MB
// y round-trip). x is L3-resident after kernel S. The quirk: stats indexed by the
// TIME position t, i.e. series (b'=t, c) -- read from the L2-resident float2 table.
__global__ void __launch_bounds__(256)
out_k(const float* __restrict__ x, const float* __restrict__ Mt,
      const float2* __restrict__ st, float* __restrict__ out) {
    const int c = blockIdx.x * 64 + threadIdx.x;
    const int b = blockIdx.y * 4 + threadIdx.y;
    if (b >= NB) return;
    const int i = b * NC + c;

#pragma unroll 1
    for (int band = 0; band < 2; ++band) {
        const float* __restrict__ Mb = Mt + band * TT * TT;
        float f[TT];
#pragma unroll
        for (int t = 0; t < TT; ++t) f[t] = 0.f;
#pragma unroll
        for (int k = 0; k < TT; ++k) {
            const float xk = x[(size_t)k * NCH + i];
#pragma unroll
            for (int t = 0; t < TT; ++t) f[t] = fmaf(Mb[k * TT + t], xk, f[t]);
        }
#pragma unroll
        for (int t = 0; t < TT; ++t) {
            const float2 s = st[(size_t)(band * TT + t) * NC + c];   // QUIRK: [t], not [b]
            out[(size_t)(band * TT + t) * NCH + i] = (f[t] - s.x) * s.y;
        }
    }
}

// ---------------- Host: Butterworth bandpass SOS + zi (reference-exact, double) ----
static Coefs make_coefs() {
    Coefs cf;
    const double bands[2][2] = {{0.05, 0.15}, {0.2, 0.4}};
    const int n = 2;  // ORDER
    for (int bd = 0; bd < 2; ++bd) {
        const double fs = 2.0;
        const double w1 = bands[bd][0], w2 = bands[bd][1];
        const double warped0 = 2.0 * fs * std::tan(M_PI * w1 / fs);
        const double warped1 = 2.0 * fs * std::tan(M_PI * w2 / fs);
        const double bw = warped1 - warped0;
        const double wo = std::sqrt(warped0 * warped1);
        std::complex<double> p_bp[4];
        for (int k = 1; k <= n; ++k) {
            std::complex<double> p = -std::exp(std::complex<double>(0.0, M_PI * (2 * k - 1) / (2.0 * n)));
            std::complex<double> plp = p * (bw / 2.0);
            std::complex<double> disc = std::sqrt(plp * plp - std::complex<double>(wo * wo, 0.0));
            p_bp[k - 1] = plp + disc;
            p_bp[n + k - 1] = plp - disc;
        }
        const double fs2 = 2.0 * fs;
        std::complex<double> prod(1.0, 0.0);
        for (int i = 0; i < 2 * n; ++i) prod *= (fs2 - p_bp[i]);
        const double gain = std::pow(bw, n) * std::pow(fs2, n) / prod.real();
        std::complex<double> p_d[4];
        for (int i = 0; i < 2 * n; ++i) p_d[i] = (fs2 + p_bp[i]) / (fs2 - p_bp[i]);
        double sos[2][6];
        int cnt = 0;
        for (int i = 0; i < 2 * n; ++i) {
            if (p_d[i].imag() > 0) {
                const double g = (cnt == 0) ? gain : 1.0;
                sos[cnt][0] = g;
                sos[cnt][1] = 0.0;
                sos[cnt][2] = -g;
                sos[cnt][3] = 1.0;
                sos[cnt][4] = -2.0 * p_d[i].real();
                sos[cnt][5] = std::norm(p_d[i]);
                ++cnt;
            }
        }
        double scale = 1.0;
        for (int s = 0; s < 2; ++s) {
            const double b0 = sos[s][0], b1 = sos[s][1], b2 = sos[s][2];
            const double a1 = sos[s][4], a2 = sos[s][5];
            const double B0 = b1 - a1 * b0, B1 = b2 - a2 * b0;
            const double det = 1.0 + a1 + a2;
            cf.b0[bd][s] = b0; cf.b1[bd][s] = b1; cf.b2[bd][s] = b2;
            cf.a1[bd][s] = a1; cf.a2[bd][s] = a2;
            cf.zi0[bd][s] = scale * (B0 + B1) / det;
            cf.zi1[bd][s] = scale * ((1.0 + a1) * B1 - a2 * B0) / det;
            scale *= (b0 + b1 + b2) / (1.0 + a1 + a2);
        }
    }
    return cf;
}

extern "C" void kernel_launch(void* const* d_in, const int* in_sizes, int n_in,
                              void* d_out, int out_size, void* d_ws, size_t ws_size,
                              hipStream_t stream) {
    const float* x = (const float*)d_in[0];
    float* out = (float*)d_out;
    float* Mt = (float*)d_ws;                                  // 20 KB at offset 0
    float2* st = (float2*)((char*)d_ws + 32768);               // 2*50*4096*8 = 3.3 MB

    const Coefs cf = make_coefs();
    build_M<<<dim3(2), dim3(64), 0, stream>>>(Mt, cf);

    dim3 blk(64, 4);
    dim3 grd(NC / 64, (NB + 3) / 4);                           // 64 x 13 = 832 blocks
    stats_k<<<grd, blk, 0, stream>>>(x, Mt, st);
    out_k<<<grd, blk, 0, stream>>>(x, Mt, st, out);
}